// Round 5
// baseline (503.839 us; speedup 1.0000x reference)
//
#include <hip/hip_runtime.h>
#include <hip/hip_bf16.h>
#include <stdint.h>
#include <math.h>

// Problem constants (B=1)
#define cH    2048
#define cQ    1024
#define cNH   32
#define cNKV  8
#define cKB   2048

#define INV_BIG   (1.0f/4194304.0f)   // 1/(2048*2048)
#define INV_SMALL (1.0f/1048576.0f)   // 1/(512*2048)

// ---------------------------------------------------------------------------
// Workspace layout (bytes). Total = 46,932,224 (<= proven 48,242,944).
#define WS_SUMS 0           // 8 doubles (5 used)
#define WS_DQ1  256         // 1024 f32
#define WS_DQ2  4352        // 1024 f32
#define WS_XQ   8448        // 1024x2048 bf16 (xq1; reused as xq2 after attention)
#define WS_WALL 4202752     // 5120x2048 bf16 weights; DEAD after fused GEMM ->
                            //   vtKBhi 8MB frag-tiles [h*32+kt], vtKBlo at +8MB,
                            //   vtPhi 1MB frag-tiles [hkv*16+kt] at +16MB, vtPlo +17MB
#define WS_QB   25174272    // 1024x2048 f32 rotated q; split-1 partial O (in-place);
                            //   reused as wqo after merge
#define WS_KB   33562880    // prompt K planes: KPhi 1MB frag-tiles, KPlo +1MB
#define WS_VB   35660032    // 1024x512 f32 v (source for vtrans)
#define WS_QN   37757184    // 1024x2048 f32 kb_q; split-0 partial O (in-place); then CTX
#define WS_ROPET 46145792   // 1024x32 float2 cos/sin table (262,144 B)
#define WS_ML   46407936    // [2][32][1024] float2 (m,l) partials (524,288 B)

// Fragment-ordered 8KB tile plane: fragment f = kk*4 + nt (kk = inner-dim>>5,
// nt = outer-dim>>4); within fragment, lane = (outer&15) + 16*((inner&31)>>3),
// elem j = inner&7. One fragment = 64 lanes x 16B = 1KB, loads coalesced.

using short8  = __attribute__((ext_vector_type(8))) short;
using floatx4 = __attribute__((ext_vector_type(4))) float;

__device__ __forceinline__ void bsplit(float x, unsigned short& hi, unsigned short& lo) {
  __hip_bfloat16 h = __float2bfloat16(x);          // RN
  float hf = __bfloat162float(h);
  __hip_bfloat16 l = __float2bfloat16(x - hf);     // exact residual, RN again
  hi = *(unsigned short*)&h;
  lo = *(unsigned short*)&l;
}

__device__ __forceinline__ unsigned short tern(float v, float ws) {
  float q = rintf(v * ws);
  q = fminf(fmaxf(q, -1.0f), 1.0f);
  return (unsigned short)(__float_as_uint(q) >> 16);
}

// ---------------------------------------------------------------------------
// RoPE cos/sin table: 1024 positions x 32 freqs, fp64 math once.
__global__ void k_ropetab(const int* __restrict__ pos, float2* __restrict__ tab) {
  int i = blockIdx.x * 256 + threadIdx.x;   // 32768
  int t = i >> 5, d = i & 31;
  double p = (double)pos[t];
  double ang = p * pow(10000.0, -(double)d / 32.0);
  tab[i] = make_float2((float)cos(ang), (float)sin(ang));
}

// ---------------------------------------------------------------------------
__global__ void k_abssum5(const float* __restrict__ w0, const float* __restrict__ w1,
                          const float* __restrict__ w2, const float* __restrict__ w3,
                          const float* __restrict__ w4, double* __restrict__ out) {
  __shared__ double red[256];
  const int seg = blockIdx.y;
  const float* w = seg == 0 ? w0 : seg == 1 ? w1 : seg == 2 ? w2 : seg == 3 ? w3 : w4;
  const int n4 = ((seg == 1 || seg == 2) ? 512 * 2048 : 2048 * 2048) / 4;
  double s = 0.0;
  for (int i = blockIdx.x * 256 + threadIdx.x; i < n4; i += gridDim.x * 256) {
    float4 x = *(const float4*)(w + (size_t)i * 4);
    s += (double)fabsf(x.x) + (double)fabsf(x.y) + (double)fabsf(x.z) + (double)fabsf(x.w);
  }
  red[threadIdx.x] = s;
  __syncthreads();
  for (int o = 128; o > 0; o >>= 1) {
    if ((int)threadIdx.x < o) red[threadIdx.x] += red[threadIdx.x + o];
    __syncthreads();
  }
  if (threadIdx.x == 0) atomicAdd(out + seg, red[0]);
}

// Fused ternary quant of Wq/Wk/Wv/Wqn (4 elems/thread; segment bounds are /4).
__global__ void k_wquant4(const float* __restrict__ Wq, const float* __restrict__ Wk,
                          const float* __restrict__ Wv, const float* __restrict__ Wqn,
                          unsigned short* __restrict__ wall, const double* __restrict__ sums) {
  size_t i = ((size_t)blockIdx.x * 256 + threadIdx.x) * 4;   // 0 .. 10485756
  const float* src; size_t off; double s; float inv;
  if (i < 4194304)      { src = Wq;  off = 0;       s = sums[0]; inv = INV_BIG; }
  else if (i < 5242880) { src = Wk;  off = 4194304; s = sums[1]; inv = INV_SMALL; }
  else if (i < 6291456) { src = Wv;  off = 5242880; s = sums[2]; inv = INV_SMALL; }
  else                  { src = Wqn; off = 6291456; s = sums[4]; inv = INV_BIG; }
  float ws = 1.0f / fmaxf((float)s * inv, 1e-5f);
  float4 x = *(const float4*)(src + (i - off));
  ushort4 o;
  o.x = tern(x.x, ws); o.y = tern(x.y, ws); o.z = tern(x.z, ws); o.w = tern(x.w, ws);
  *(ushort4*)(wall + i) = o;
}

// Single-weight ternary quant (Wo), 4 elems/thread.
__global__ void k_wquant(const float* __restrict__ w, unsigned short* __restrict__ wq,
                         const double* __restrict__ sum, float inv_n) {
  size_t i = ((size_t)blockIdx.x * 256 + threadIdx.x) * 4;
  float ws = 1.0f / fmaxf((float)(*sum) * inv_n, 1e-5f);
  float4 x = *(const float4*)(w + i);
  ushort4 o;
  o.x = tern(x.x, ws); o.y = tern(x.y, ws); o.z = tern(x.z, ws); o.w = tern(x.w, ws);
  *(ushort4*)(wq + i) = o;
}

// Per-token int8 absmax activation quant -> bf16 integer values (float4 path).
__global__ void k_aquant(const float* __restrict__ x, unsigned short* __restrict__ xq,
                         float* __restrict__ dq, int K) {
  int t = blockIdx.x;
  const float4* xr = (const float4*)(x + (size_t)t * K);
  const int K4 = K / 4;
  __shared__ float red[256];
  float m = 0.0f;
  for (int i = threadIdx.x; i < K4; i += 256) {
    float4 v = xr[i];
    m = fmaxf(m, fmaxf(fmaxf(fabsf(v.x), fabsf(v.y)), fmaxf(fabsf(v.z), fabsf(v.w))));
  }
  red[threadIdx.x] = m;
  __syncthreads();
  for (int o = 128; o > 0; o >>= 1) {
    if ((int)threadIdx.x < o) red[threadIdx.x] = fmaxf(red[threadIdx.x], red[threadIdx.x + o]);
    __syncthreads();
  }
  float amax = fmaxf(red[0], 1e-5f);
  float as = 127.0f / amax;
  ushort4* xo = (ushort4*)(xq + (size_t)t * K);
  for (int i = threadIdx.x; i < K4; i += 256) {
    float4 v = xr[i];
    ushort4 o;
    float q;
    q = fminf(fmaxf(rintf(v.x * as), -128.0f), 127.0f); o.x = (unsigned short)(__float_as_uint(q) >> 16);
    q = fminf(fmaxf(rintf(v.y * as), -128.0f), 127.0f); o.y = (unsigned short)(__float_as_uint(q) >> 16);
    q = fminf(fmaxf(rintf(v.z * as), -128.0f), 127.0f); o.z = (unsigned short)(__float_as_uint(q) >> 16);
    q = fminf(fmaxf(rintf(v.w * as), -128.0f), 127.0f); o.w = (unsigned short)(__float_as_uint(q) >> 16);
    xo[i] = o;
  }
  if (threadIdx.x == 0) dq[t] = amax / 127.0f;
}

// ---------------------------------------------------------------------------
// bf16-MFMA BitLinear GEMM, 128x128 tiles. RoPE fused into the epilogue:
// pair (d,d+32) = (h,h+2) lives in the same thread; Q (bx<16) rotated fp32,
// K (bx 16..19) rotated + RN-bsplit into FRAGMENT-ordered hi/lo tile planes.
__global__ __launch_bounds__(256) void k_gemm_mfma(
    const unsigned short* __restrict__ Aq, const unsigned short* __restrict__ Ball,
    const float* __restrict__ adq, const double* __restrict__ sums,
    const float2* __restrict__ ropetab,
    float* __restrict__ oQ, unsigned short* __restrict__ oKhi,
    unsigned short* __restrict__ oKlo,
    float* __restrict__ oV, float* __restrict__ oQN, int mode) {
  __shared__ unsigned short As[128 * 72];
  __shared__ unsigned short Bs[128 * 72];
  const int t = threadIdx.x;
  const int lane = t & 63;
  const int row16 = lane & 15, q = lane >> 4;
  const int w = t >> 6;
  const int wm = (w >> 1) * 64, wn = (w & 1) * 64;
  const int bx = blockIdx.x;
  const int m0 = blockIdx.y * 128;
  const unsigned short* Bp = Ball + (size_t)bx * 128 * 2048;

  floatx4 acc[4][4];
#pragma unroll
  for (int g = 0; g < 4; ++g)
#pragma unroll
    for (int h = 0; h < 4; ++h) acc[g][h] = (floatx4){0.f, 0.f, 0.f, 0.f};

  for (int k0 = 0; k0 < 2048; k0 += 64) {
#pragma unroll
    for (int i = 0; i < 4; ++i) {
      int c = t + 256 * i;
      int row = c >> 3, g8 = c & 7;
      *(uint4*)&As[row * 72 + g8 * 8] =
          *(const uint4*)(Aq + (size_t)(m0 + row) * 2048 + k0 + g8 * 8);
      *(uint4*)&Bs[row * 72 + g8 * 8] =
          *(const uint4*)(Bp + (size_t)row * 2048 + k0 + g8 * 8);
    }
    __syncthreads();
#pragma unroll
    for (int kk = 0; kk < 2; ++kk) {
      short8 af[4], bf[4];
#pragma unroll
      for (int g = 0; g < 4; ++g)
        af[g] = *(const short8*)&As[(wm + g * 16 + row16) * 72 + kk * 32 + q * 8];
#pragma unroll
      for (int h = 0; h < 4; ++h)
        bf[h] = *(const short8*)&Bs[(wn + h * 16 + row16) * 72 + kk * 32 + q * 8];
#pragma unroll
      for (int g = 0; g < 4; ++g)
#pragma unroll
        for (int h = 0; h < 4; ++h)
          acc[g][h] = __builtin_amdgcn_mfma_f32_16x16x32_bf16(af[g], bf[h], acc[g][h], 0, 0, 0);
    }
    __syncthreads();
  }

  float* outp = nullptr; int Nout = 0, nb0; float wdq;
  if (mode == 1)      { outp = oQ;  Nout = 2048; nb0 = bx * 128;        wdq = fmaxf((float)sums[3] * INV_BIG,   1e-5f); }
  else if (bx < 16)   { outp = oQ;  Nout = 2048; nb0 = bx * 128;        wdq = fmaxf((float)sums[0] * INV_BIG,   1e-5f); }
  else if (bx < 20)   {             Nout = 512;  nb0 = (bx - 16) * 128; wdq = fmaxf((float)sums[1] * INV_SMALL, 1e-5f); }
  else if (bx < 24)   { outp = oV;  Nout = 512;  nb0 = (bx - 20) * 128; wdq = fmaxf((float)sums[2] * INV_SMALL, 1e-5f); }
  else                { outp = oQN; Nout = 2048; nb0 = (bx - 24) * 128; wdq = fmaxf((float)sums[4] * INV_BIG,   1e-5f); }

  if (mode == 0 && bx < 20) {
    // RoPE epilogue. head-relative d = (wn + h*16 + row16) & 63 = h*16 + row16.
#pragma unroll
    for (int g = 0; g < 4; ++g)
#pragma unroll
      for (int r = 0; r < 4; ++r) {
        int m = m0 + wm + g * 16 + q * 4 + r;
        float s = adq[m] * wdq;
        float2 cs0 = ropetab[m * 32 + row16];        // d = row16
        float2 cs1 = ropetab[m * 32 + 16 + row16];   // d = 16 + row16
        float v0 = acc[g][0][r] * s, v1 = acc[g][1][r] * s;
        float v2 = acc[g][2][r] * s, v3 = acc[g][3][r] * s;
        float o0 = v0 * cs0.x - v2 * cs0.y;
        float o2 = v2 * cs0.x + v0 * cs0.y;
        float o1 = v1 * cs1.x - v3 * cs1.y;
        float o3 = v3 * cs1.x + v1 * cs1.y;
        if (bx < 16) {   // Q: fp32
          size_t base = (size_t)m * Nout + nb0 + wn;
          outp[base + row16]      = o0;
          outp[base + 16 + row16] = o1;
          outp[base + 32 + row16] = o2;
          outp[base + 48 + row16] = o3;
        } else {
          // K: RN-bsplit into fragment-ordered hi/lo planes.
          // value o_h: key rr = m&63 (tile kt_ = m>>6), d = h*16 + row16.
          // frag = (h>>1)*4 + (rr>>4); lane = (rr&15) + 16*((h&1)*2 + (row16>>3));
          // j = row16&7.
          int hkv_ = (nb0 + wn) >> 6;
          int kt_ = m >> 6, rr = m & 63;
          size_t tb = ((size_t)(hkv_ * 16 + kt_)) * 4096;
          int lbase = (rr & 15) + ((row16 >> 3) << 4);
          int ntb = (rr >> 4) * 512 + (row16 & 7);
          unsigned short hi, lo; int ix;
          bsplit(o0, hi, lo); ix = ntb + (lbase     ) * 8;          oKhi[tb + ix] = hi; oKlo[tb + ix] = lo;
          bsplit(o1, hi, lo); ix = ntb + (lbase + 32) * 8;          oKhi[tb + ix] = hi; oKlo[tb + ix] = lo;
          bsplit(o2, hi, lo); ix = ntb + (lbase     ) * 8 + 2048;   oKhi[tb + ix] = hi; oKlo[tb + ix] = lo;
          bsplit(o3, hi, lo); ix = ntb + (lbase + 32) * 8 + 2048;   oKhi[tb + ix] = hi; oKlo[tb + ix] = lo;
        }
      }
  } else {
#pragma unroll
    for (int g = 0; g < 4; ++g)
#pragma unroll
      for (int r = 0; r < 4; ++r) {
        int m = m0 + wm + g * 16 + q * 4 + r;
        float s = adq[m] * wdq;
#pragma unroll
        for (int h = 0; h < 4; ++h)
          outp[(size_t)m * Nout + nb0 + wn + h * 16 + row16] = acc[g][h][r] * s;
      }
  }
}

// ---------------------------------------------------------------------------
// Merged prep. All outputs are 8KB fragment-ordered ushort tile planes (see
// header comment) so attention loads fragments global->VGPR fully coalesced.
//   blocks [0,1024):    vtKB  (transpose kbv -> V^T, RN-bsplit hi/lo planes)
//   blocks [1024,1152): vtP   (transpose Vb  -> V^T, RN-bsplit hi/lo planes)
//   blocks >= 1152:     kbk   in-place tile split [key][d] -> [hi 8KB | lo 8KB]
__global__ __launch_bounds__(256) void k_prep(
    const float* __restrict__ kbv, const float* __restrict__ Vb,
    unsigned short* __restrict__ vtKBhi, unsigned short* __restrict__ vtPhi,
    float* __restrict__ kbk) {
  const int b = blockIdx.x;
  const int t = threadIdx.x;
  if (b >= 1152) {
    float* tile = kbk + (size_t)(b - 1152) * 4096;   // 64x64 f32 [key][d], contiguous
    float v[2][8];
#pragma unroll
    for (int u = 0; u < 2; ++u) {
      int task = t + 256 * u;            // 512 tasks: key r = task>>3, d-slot s = task&7
      int r = task >> 3, s = task & 7;
      *(float4*)&v[u][0] = *(const float4*)(tile + r * 64 + s * 8);
      *(float4*)&v[u][4] = *(const float4*)(tile + r * 64 + s * 8 + 4);
    }
    __syncthreads();                     // all reads before any in-place write
    unsigned short* up = (unsigned short*)tile;
#pragma unroll
    for (int u = 0; u < 2; ++u) {
      int task = t + 256 * u;
      int r = task >> 3, s = task & 7;   // element (key=r, d=s*8+j)
      union { unsigned short u16[8]; uint4 q; } hi, lo;
#pragma unroll
      for (int j = 0; j < 8; ++j) bsplit(v[u][j], hi.u16[j], lo.u16[j]);
      // K-frag: frag = (d>>5)*4 + (key>>4); lane = (key&15) + 16*((d&31)>>3); j = d&7
      size_t off = (size_t)(((s >> 2) * 4 + (r >> 4)) * 512 + ((r & 15) + ((s & 3) << 4)) * 8);
      *(uint4*)(up + off)        = hi.q;
      *(uint4*)(up + 4096 + off) = lo.q;
    }
    return;
  }
  __shared__ float Lf[64 * 65];
  const float* src; unsigned short *dhi, *dlo; int srcStride;
  if (b < 1024) {
    int h = b >> 5, kt = b & 31;
    src = kbv + ((size_t)h * cKB + kt * 64) * 64; srcStride = 64;
    dhi = vtKBhi + (size_t)b * 4096; dlo = dhi + 4194304;
  } else {
    int bb = b - 1024;
    int hkv = bb >> 4, kt = bb & 15;
    src = Vb + (size_t)(kt * 64) * 512 + hkv * 64; srcStride = 512;
    dhi = vtPhi + (size_t)bb * 4096; dlo = dhi + 524288;
  }
#pragma unroll
  for (int i = 0; i < 4; ++i) {
    int c = t + 256 * i;
    int row = c >> 4, c4 = (c & 15) * 4;       // row = key, col = d
    float4 x = *(const float4*)(src + (size_t)row * srcStride + c4);
    Lf[row * 65 + c4 + 0] = x.x;
    Lf[row * 65 + c4 + 1] = x.y;
    Lf[row * 65 + c4 + 2] = x.z;
    Lf[row * 65 + c4 + 3] = x.w;
  }
  __syncthreads();
#pragma unroll
  for (int u = 0; u < 2; ++u) {
    int task = t + 256 * u;                    // d = task>>3, key slot s = task&7
    int d = task >> 3, s = task & 7;           // element (d, key=s*8+j)
    union { unsigned short u16[8]; uint4 q; } hi, lo;
#pragma unroll
    for (int j = 0; j < 8; ++j) bsplit(Lf[(s * 8 + j) * 65 + d], hi.u16[j], lo.u16[j]);
    // V^T-frag: frag = (key>>5)*4 + (d>>4); lane = (d&15) + 16*((key&31)>>3); j = key&7
    size_t off = (size_t)(((s >> 2) * 4 + (d >> 4)) * 512 + ((d & 15) + ((s & 3) << 4)) * 8);
    *(uint4*)(dhi + off) = hi.q;
    *(uint4*)(dlo + off) = lo.q;
  }
}

// ---------------------------------------------------------------------------
// Split-bf16 MFMA flash attention with 2-way KV-SPLIT (blockIdx.z):
//   z=0: the 32 KB tiles (uses kb_q only)   -> partial O over qnctx (kb_q)
//   z=1: the causal prompt tiles (uses Qr)  -> partial O over Qb (rotated q)
// Each block's output cells are read only by its own prologue (per-wave WAR),
// so partials need no extra storage; (m,l) go to the ml buffer. Grid 1024
// blocks = 4 blocks/CU = 16 waves/CU (prior rounds were latency-bound at 8).
// K/V fragments load register-direct from fragment-ordered global tiles.
__global__ __launch_bounds__(256, 4) void k_attn_mfma(
    float* __restrict__ Qr, float* __restrict__ qnctx,
    const unsigned short* __restrict__ KPhi,    // prompt K planes, lo at +524288
    const unsigned short* __restrict__ kbkS,    // KB K tiles [h*32+kt][hi 4096 | lo 4096]
    const unsigned short* __restrict__ vtKBhi,  // KB V^T planes, lo at +4194304
    const unsigned short* __restrict__ vtPhi,   // prompt V^T planes, lo at +524288
    float2* __restrict__ ml) {                  // [2][32][1024] (m,l)
  __shared__ __attribute__((aligned(16))) unsigned int Pbuf[4][16 * 68];   // per-wave

  const int t = threadIdx.x;
  const int lane = t & 63;
  const int col = lane & 15;
  const int quad = lane >> 4;
  const int w = t >> 6;
  const int h = blockIdx.x;
  const int q0 = blockIdx.y * 64;
  const int split = blockIdx.z;
  const int hkv = h >> 2;
  const float kbbias = 0.69314718055994531f;   // log(4096)-log(2048)
  unsigned int* Pw = &Pbuf[w][0];
  const int fl = lane * 8;                     // fragment lane offset (ushorts)

  // Per-split bases (wave-uniform SGPRs).
  const unsigned short *Kb, *Vbp; int Kstr, Kloo, Vloo, ntiles;
  float* obase;
  if (split == 0) {
    Kb = kbkS + (size_t)h * 32 * 8192;   Kstr = 8192; Kloo = 4096;
    Vbp = vtKBhi + (size_t)h * 32 * 4096; Vloo = 4194304;
    ntiles = 32; obase = qnctx;
  } else {
    Kb = KPhi + (size_t)hkv * 16 * 4096; Kstr = 4096; Kloo = 524288;
    Vbp = vtPhi + (size_t)hkv * 16 * 4096; Vloo = 524288;
    ntiles = (q0 >> 6) + 1; obase = Qr;
  }

  // Q prologue: one set only (split 0: kb_q, split 1: rotated prompt q).
  short8 qh[2], ql[2];
  {
    const float* qbase = split == 0 ? qnctx : Qr;
#pragma unroll
    for (int kk = 0; kk < 2; ++kk) {
      const size_t off = (size_t)(q0 + w * 16 + col) * 2048 + h * 64 + kk * 32 + quad * 8;
      float4 a = *(const float4*)(qbase + off);
      float4 b = *(const float4*)(qbase + off + 4);
      float xs[8] = {a.x, a.y, a.z, a.w, b.x, b.y, b.z, b.w};
#pragma unroll
      for (int j = 0; j < 8; ++j) {
        unsigned short hi, lo;
        bsplit(xs[j] * 0.125f, hi, lo);   // fold 1/sqrt(64), exact
        qh[kk][j] = (short)hi; ql[kk][j] = (short)lo;
      }
    }
  }

  floatx4 acco[4];
  float m_[4], l_[4];
#pragma unroll
  for (int nt = 0; nt < 4; ++nt) acco[nt] = (floatx4){0.f, 0.f, 0.f, 0.f};
#pragma unroll
  for (int r = 0; r < 4; ++r) { m_[r] = -3.0e38f; l_[r] = 0.f; }

  short8 kh[2][4], kl[2][4];   // K fragments (hi/lo), current tile
  short8 vh[2][4], vl[2][4];   // V^T fragments (hi/lo), current tile

  auto loadK = [&](int kt2) {
    const unsigned short* ph = Kb + (size_t)kt2 * Kstr;
    const unsigned short* pl = ph + Kloo;
#pragma unroll
    for (int kk = 0; kk < 2; ++kk)
#pragma unroll
      for (int nt = 0; nt < 4; ++nt) {
        kh[kk][nt] = *(const short8*)(ph + (kk * 4 + nt) * 512 + fl);
        kl[kk][nt] = *(const short8*)(pl + (kk * 4 + nt) * 512 + fl);
      }
  };
  auto loadV = [&](int kt2) {
    const unsigned short* ph = Vbp + (size_t)kt2 * 4096;
    const unsigned short* pl = ph + Vloo;
#pragma unroll
    for (int kk = 0; kk < 2; ++kk)
#pragma unroll
      for (int nt = 0; nt < 4; ++nt) {
        vh[kk][nt] = *(const short8*)(ph + (kk * 4 + nt) * 512 + fl);
        vl[kk][nt] = *(const short8*)(pl + (kk * 4 + nt) * 512 + fl);
      }
  };

  loadK(0);   // prologue

  for (int kt = 0; kt < ntiles; ++kt) {
    loadV(kt);                          // in flight during QK+softmax
    __builtin_amdgcn_s_barrier();       // convergence only (no shared staging)

    floatx4 accs[4];
#pragma unroll
    for (int nt = 0; nt < 4; ++nt) accs[nt] = (floatx4){0.f, 0.f, 0.f, 0.f};
#pragma unroll
    for (int kk = 0; kk < 2; ++kk)
#pragma unroll
      for (int nt = 0; nt < 4; ++nt) {
        accs[nt] = __builtin_amdgcn_mfma_f32_16x16x32_bf16(qh[kk], kh[kk][nt], accs[nt], 0, 0, 0);
        accs[nt] = __builtin_amdgcn_mfma_f32_16x16x32_bf16(ql[kk], kh[kk][nt], accs[nt], 0, 0, 0);
        accs[nt] = __builtin_amdgcn_mfma_f32_16x16x32_bf16(qh[kk], kl[kk][nt], accs[nt], 0, 0, 0);
      }

    // Bias/mask: split 0 = uniform KB bias; split 1 = none except causal mask
    // on the final (diagonal) tile.
    float sv[4][4];
    if (split == 0) {
#pragma unroll
      for (int nt = 0; nt < 4; ++nt)
#pragma unroll
        for (int r = 0; r < 4; ++r) sv[nt][r] = accs[nt][r] + kbbias;
    } else if (kt < ntiles - 1) {
#pragma unroll
      for (int nt = 0; nt < 4; ++nt)
#pragma unroll
        for (int r = 0; r < 4; ++r) sv[nt][r] = accs[nt][r];
    } else {
#pragma unroll
      for (int nt = 0; nt < 4; ++nt) {
        int kl_ = nt * 16 + col;
#pragma unroll
        for (int r = 0; r < 4; ++r) {
          int ql_ = w * 16 + quad * 4 + r;
          sv[nt][r] = accs[nt][r] + ((kl_ <= ql_) ? 0.0f : -1e9f);
        }
      }
    }
#pragma unroll
    for (int r = 0; r < 4; ++r) {
      float rmax = fmaxf(fmaxf(sv[0][r], sv[1][r]), fmaxf(sv[2][r], sv[3][r]));
#pragma unroll
      for (int off = 8; off; off >>= 1) rmax = fmaxf(rmax, __shfl_xor(rmax, off));
      float mnew = fmaxf(m_[r], rmax);
      float alpha = __expf(m_[r] - mnew);
      float psum = 0.f;
#pragma unroll
      for (int nt = 0; nt < 4; ++nt) {
        float p = __expf(sv[nt][r] - mnew);
        sv[nt][r] = p;
        psum += p;
      }
#pragma unroll
      for (int off = 8; off; off >>= 1) psum += __shfl_xor(psum, off);
      l_[r] = l_[r] * alpha + psum;
      m_[r] = mnew;
#pragma unroll
      for (int nt = 0; nt < 4; ++nt) acco[nt][r] *= alpha;
    }

    // Prefetch next tile's K (WAR on kh/kl keeps these after the QK MFMAs;
    // in flight during P-pack + PV). Clamped redundant load on last tile.
    loadK(kt + 1 < ntiles ? kt + 1 : kt);

    // P truncation split -> packed hi|lo<<16 (err <= 2^-16 * p; p in [0,1]).
#pragma unroll
    for (int nt = 0; nt < 4; ++nt)
#pragma unroll
      for (int r = 0; r < 4; ++r) {
        unsigned xb = __float_as_uint(sv[nt][r]);
        float hf = __uint_as_float(xb & 0xffff0000u);
        unsigned db = __float_as_uint(sv[nt][r] - hf);
        Pw[(quad * 4 + r) * 68 + nt * 16 + col] = (xb >> 16) | (db & 0xffff0000u);
      }

#pragma unroll
    for (int kk = 0; kk < 2; ++kk) {
      uint4 pa = *(const uint4*)&Pw[col * 68 + kk * 32 + quad * 8];
      uint4 pb = *(const uint4*)&Pw[col * 68 + kk * 32 + quad * 8 + 4];
      union { unsigned int u[4]; short8 s; } uh, ul;
      uh.u[0] = (pa.x & 0xffffu) | (pa.y << 16);
      uh.u[1] = (pa.z & 0xffffu) | (pa.w << 16);
      uh.u[2] = (pb.x & 0xffffu) | (pb.y << 16);
      uh.u[3] = (pb.z & 0xffffu) | (pb.w << 16);
      ul.u[0] = (pa.x >> 16) | (pa.y & 0xffff0000u);
      ul.u[1] = (pa.z >> 16) | (pa.w & 0xffff0000u);
      ul.u[2] = (pb.x >> 16) | (pb.y & 0xffff0000u);
      ul.u[3] = (pb.z >> 16) | (pb.w & 0xffff0000u);
      short8 ph8 = uh.s, pl8 = ul.s;
#pragma unroll
      for (int nt = 0; nt < 4; ++nt) {
        acco[nt] = __builtin_amdgcn_mfma_f32_16x16x32_bf16(ph8, vh[kk][nt], acco[nt], 0, 0, 0);
        acco[nt] = __builtin_amdgcn_mfma_f32_16x16x32_bf16(pl8, vh[kk][nt], acco[nt], 0, 0, 0);
        acco[nt] = __builtin_amdgcn_mfma_f32_16x16x32_bf16(ph8, vl[kk][nt], acco[nt], 0, 0, 0);
      }
    }
  }

  // Epilogue: UNNORMALIZED partial O over this block's own Q cells + (m,l).
#pragma unroll
  for (int r = 0; r < 4; ++r) {
    int row = q0 + w * 16 + quad * 4 + r;
#pragma unroll
    for (int nt = 0; nt < 4; ++nt)
      obase[(size_t)row * 2048 + h * 64 + nt * 16 + col] = acco[nt][r];
    if (col == 0)
      ml[(size_t)(split * 32 + h) * 1024 + row] = make_float2(m_[r], l_[r]);
  }
}

// ---------------------------------------------------------------------------
// Merge the two KV-split partials: ctx = (O0*e^(m0-m) + O1*e^(m1-m)) / l.
// O0 lives in qnctx (KB partial), O1 in Qb (prompt partial); writes qnctx.
__global__ __launch_bounds__(256) void k_merge(
    float* __restrict__ qnctx, const float* __restrict__ Qb,
    const float2* __restrict__ ml) {
  int task = blockIdx.x * 16 + (threadIdx.x >> 4);   // 32768 = 32h x 1024q
  int h = task >> 10, q = task & 1023;
  float2 a = ml[h * 1024 + q];            // split 0 (m0, l0)
  float2 c = ml[32768 + h * 1024 + q];    // split 1 (m1, l1)
  float mm = fmaxf(a.x, c.x);
  float e0 = __expf(a.x - mm), e1 = __expf(c.x - mm);
  float inv = 1.0f / (a.y * e0 + c.y * e1);
  float a0 = e0 * inv, a1 = e1 * inv;
  size_t off = (size_t)q * 2048 + h * 64 + (threadIdx.x & 15) * 4;
  float4 o0 = *(const float4*)(qnctx + off);
  float4 o1 = *(const float4*)(Qb + off);
  float4 o;
  o.x = o0.x * a0 + o1.x * a1;
  o.y = o0.y * a0 + o1.y * a1;
  o.z = o0.z * a0 + o1.z * a1;
  o.w = o0.w * a0 + o1.w * a1;
  *(float4*)(qnctx + off) = o;
}

// ---------------------------------------------------------------------------
extern "C" void kernel_launch(void* const* d_in, const int* in_sizes, int n_in,
                              void* d_out, int out_size, void* d_ws, size_t ws_size,
                              hipStream_t stream) {
  (void)in_sizes; (void)n_in; (void)out_size; (void)ws_size;
  const float* hidden = (const float*)d_in[0];
  float* kbk = (float*)d_in[2];              // tile-split in place (restored each launch)
  const float* kbv = (const float*)d_in[3];
  const float* Wq  = (const float*)d_in[4];
  const float* Wk  = (const float*)d_in[5];
  const float* Wv  = (const float*)d_in[6];
  const float* Wo  = (const float*)d_in[7];
  const float* Wqn = (const float*)d_in[8];
  const int*   pos = (const int*)d_in[9];

  char* ws = (char*)d_ws;
  double* sums = (double*)(ws + WS_SUMS);
  float* dq1 = (float*)(ws + WS_DQ1);
  float* dq2 = (float*)(ws + WS_DQ2);
  unsigned short* xq   = (unsigned short*)(ws + WS_XQ);
  unsigned short* wall = (unsigned short*)(ws + WS_WALL);
  unsigned short* vtKBhi = (unsigned short*)(ws + WS_WALL);              // after GEMM
  unsigned short* vtPhi  = (unsigned short*)(ws + WS_WALL + 16777216);   // after GEMM
  unsigned short* wqo  = (unsigned short*)(ws + WS_QB);                  // after merge
  float* Qb  = (float*)(ws + WS_QB);
  unsigned short* KPhi = (unsigned short*)(ws + WS_KB);                  // prompt K hi
  unsigned short* KPlo = KPhi + 524288;                                  // prompt K lo
  float* Vb  = (float*)(ws + WS_VB);
  float* QNC = (float*)(ws + WS_QN);   // kb_q, then split-0 partial, then CTX
  float2* ropetab = (float2*)(ws + WS_ROPET);
  float2* ml = (float2*)(ws + WS_ML);

  hipMemsetAsync(sums, 0, 64, stream);

  k_ropetab<<<128, 256, 0, stream>>>(pos, ropetab);
  k_abssum5<<<dim3(128, 5), 256, 0, stream>>>(Wq, Wk, Wv, Wo, Wqn, sums);
  k_wquant4<<<10240, 256, 0, stream>>>(Wq, Wk, Wv, Wqn, wall, sums);
  k_aquant<<<cQ, 256, 0, stream>>>(hidden, xq, dq1, cH);

  // Fused Q/K/V/QN GEMM with RoPE epilogue: 128x128 tiles, grid 40x8
  k_gemm_mfma<<<dim3(40, 8), 256, 0, stream>>>(xq, wall, dq1, sums, ropetab,
                                               Qb, KPhi, KPlo, Vb, QNC, 0);

  // V transposes (1152 blocks) + kbk in-place tile split (1024 blocks)
  k_prep<<<1152 + 1024, 256, 0, stream>>>(kbv, Vb, vtKBhi, vtPhi, kbk);

  // 2-way KV-split attention: z=0 KB tiles, z=1 prompt tiles (4 blocks/CU)
  k_attn_mfma<<<dim3(cNH, cQ / 64, 2), 256, 0, stream>>>(
      Qb, QNC, KPhi, (const unsigned short*)kbk, vtKBhi, vtPhi, ml);

  // Merge partials into ctx (must precede wqo overwrite of Qb)
  k_merge<<<2048, 256, 0, stream>>>(QNC, Qb, ml);

  k_wquant<<<4096, 256, 0, stream>>>(Wo, wqo, sums + 3, INV_BIG);
  k_aquant<<<cQ, 256, 0, stream>>>(QNC, xq, dq2, cH);

  // O projection: 128x128 tiles, grid 16x8
  k_gemm_mfma<<<dim3(16, 8), 256, 0, stream>>>(xq, wqo, dq2, sums, ropetab,
                                               (float*)d_out, nullptr, nullptr,
                                               nullptr, nullptr, 1);
}

// Round 7
// 371.846 us; speedup vs baseline: 1.3550x; 1.3550x over previous
//
#include <hip/hip_runtime.h>
#include <hip/hip_bf16.h>
#include <stdint.h>
#include <math.h>

// Problem constants (B=1)
#define cH    2048
#define cQ    1024
#define cNH   32
#define cNKV  8
#define cKB   2048

#define INV_BIG   (1.0f/4194304.0f)   // 1/(2048*2048)
#define INV_SMALL (1.0f/1048576.0f)   // 1/(512*2048)

// ---------------------------------------------------------------------------
// Workspace layout (bytes). Total = 46,407,936 (<= proven 48,242,944).
#define WS_SUMS 0           // 8 doubles (5 used)
#define WS_DQ1  256         // 1024 f32
#define WS_DQ2  4352        // 1024 f32
#define WS_XQ   8448        // 1024x2048 bf16 (xq1; reused as xq2 after attention)
#define WS_WALL 4202752     // 5120x2048 bf16 weights; DEAD after fused GEMM ->
                            //   vtKBhi 8MB frag-tiles [h*32+kt], vtKBlo at +8MB,
                            //   vtPhi 1MB frag-tiles [hkv*16+kt] at +16MB, vtPlo +17MB
#define WS_QB   25174272    // 1024x2048 f32 rotated q; reused as wqo after attn
#define WS_KB   33562880    // prompt K planes: KPhi 1MB frag-tiles, KPlo +1MB
#define WS_VB   35660032    // 1024x512 f32 v (source for vtrans)
#define WS_QN   37757184    // 1024x2048 f32 kb_q; reused as CTX (same rows+cols per block)
#define WS_ROPET 46145792   // 1024x32 float2 cos/sin table (262,144 B)

// Fragment-ordered 8KB tile plane: fragment f = kk*4 + nt (kk = inner-dim>>5,
// nt = outer-dim>>4); within fragment, lane = (outer&15) + 16*((inner&31)>>3),
// elem j = inner&7. One fragment = 64 lanes x 16B = 1KB, loads coalesced.

using short8  = __attribute__((ext_vector_type(8))) short;
using floatx4 = __attribute__((ext_vector_type(4))) float;

__device__ __forceinline__ void bsplit(float x, unsigned short& hi, unsigned short& lo) {
  __hip_bfloat16 h = __float2bfloat16(x);          // RN
  float hf = __bfloat162float(h);
  __hip_bfloat16 l = __float2bfloat16(x - hf);     // exact residual, RN again
  hi = *(unsigned short*)&h;
  lo = *(unsigned short*)&l;
}

__device__ __forceinline__ unsigned short tern(float v, float ws) {
  float q = rintf(v * ws);
  q = fminf(fmaxf(q, -1.0f), 1.0f);
  return (unsigned short)(__float_as_uint(q) >> 16);
}

// Async 16B global->LDS (direct-to-shared DMA; dest = wave-uniform base + lane*16).
__device__ __forceinline__ void gload16(const void* g, void* l) {
  __builtin_amdgcn_global_load_lds((const __attribute__((address_space(1))) void*)g,
                                   (__attribute__((address_space(3))) void*)l, 16, 0, 0);
}

// ---------------------------------------------------------------------------
// RoPE cos/sin table: 1024 positions x 32 freqs, fp64 math once.
__global__ void k_ropetab(const int* __restrict__ pos, float2* __restrict__ tab) {
  int i = blockIdx.x * 256 + threadIdx.x;   // 32768
  int t = i >> 5, d = i & 31;
  double p = (double)pos[t];
  double ang = p * pow(10000.0, -(double)d / 32.0);
  tab[i] = make_float2((float)cos(ang), (float)sin(ang));
}

// ---------------------------------------------------------------------------
__global__ void k_abssum5(const float* __restrict__ w0, const float* __restrict__ w1,
                          const float* __restrict__ w2, const float* __restrict__ w3,
                          const float* __restrict__ w4, double* __restrict__ out) {
  __shared__ double red[256];
  const int seg = blockIdx.y;
  const float* w = seg == 0 ? w0 : seg == 1 ? w1 : seg == 2 ? w2 : seg == 3 ? w3 : w4;
  const int n4 = ((seg == 1 || seg == 2) ? 512 * 2048 : 2048 * 2048) / 4;
  double s = 0.0;
  for (int i = blockIdx.x * 256 + threadIdx.x; i < n4; i += gridDim.x * 256) {
    float4 x = *(const float4*)(w + (size_t)i * 4);
    s += (double)fabsf(x.x) + (double)fabsf(x.y) + (double)fabsf(x.z) + (double)fabsf(x.w);
  }
  red[threadIdx.x] = s;
  __syncthreads();
  for (int o = 128; o > 0; o >>= 1) {
    if ((int)threadIdx.x < o) red[threadIdx.x] += red[threadIdx.x + o];
    __syncthreads();
  }
  if (threadIdx.x == 0) atomicAdd(out + seg, red[0]);
}

// Fused ternary quant of Wq/Wk/Wv/Wqn (4 elems/thread; segment bounds are /4).
__global__ void k_wquant4(const float* __restrict__ Wq, const float* __restrict__ Wk,
                          const float* __restrict__ Wv, const float* __restrict__ Wqn,
                          unsigned short* __restrict__ wall, const double* __restrict__ sums) {
  size_t i = ((size_t)blockIdx.x * 256 + threadIdx.x) * 4;   // 0 .. 10485756
  const float* src; size_t off; double s; float inv;
  if (i < 4194304)      { src = Wq;  off = 0;       s = sums[0]; inv = INV_BIG; }
  else if (i < 5242880) { src = Wk;  off = 4194304; s = sums[1]; inv = INV_SMALL; }
  else if (i < 6291456) { src = Wv;  off = 5242880; s = sums[2]; inv = INV_SMALL; }
  else                  { src = Wqn; off = 6291456; s = sums[4]; inv = INV_BIG; }
  float ws = 1.0f / fmaxf((float)s * inv, 1e-5f);
  float4 x = *(const float4*)(src + (i - off));
  ushort4 o;
  o.x = tern(x.x, ws); o.y = tern(x.y, ws); o.z = tern(x.z, ws); o.w = tern(x.w, ws);
  *(ushort4*)(wall + i) = o;
}

// Single-weight ternary quant (Wo), 4 elems/thread.
__global__ void k_wquant(const float* __restrict__ w, unsigned short* __restrict__ wq,
                         const double* __restrict__ sum, float inv_n) {
  size_t i = ((size_t)blockIdx.x * 256 + threadIdx.x) * 4;
  float ws = 1.0f / fmaxf((float)(*sum) * inv_n, 1e-5f);
  float4 x = *(const float4*)(w + i);
  ushort4 o;
  o.x = tern(x.x, ws); o.y = tern(x.y, ws); o.z = tern(x.z, ws); o.w = tern(x.w, ws);
  *(ushort4*)(wq + i) = o;
}

// Per-token int8 absmax activation quant -> bf16 integer values (float4 path).
__global__ void k_aquant(const float* __restrict__ x, unsigned short* __restrict__ xq,
                         float* __restrict__ dq, int K) {
  int t = blockIdx.x;
  const float4* xr = (const float4*)(x + (size_t)t * K);
  const int K4 = K / 4;
  __shared__ float red[256];
  float m = 0.0f;
  for (int i = threadIdx.x; i < K4; i += 256) {
    float4 v = xr[i];
    m = fmaxf(m, fmaxf(fmaxf(fabsf(v.x), fabsf(v.y)), fmaxf(fabsf(v.z), fabsf(v.w))));
  }
  red[threadIdx.x] = m;
  __syncthreads();
  for (int o = 128; o > 0; o >>= 1) {
    if ((int)threadIdx.x < o) red[threadIdx.x] = fmaxf(red[threadIdx.x], red[threadIdx.x + o]);
    __syncthreads();
  }
  float amax = fmaxf(red[0], 1e-5f);
  float as = 127.0f / amax;
  ushort4* xo = (ushort4*)(xq + (size_t)t * K);
  for (int i = threadIdx.x; i < K4; i += 256) {
    float4 v = xr[i];
    ushort4 o;
    float q;
    q = fminf(fmaxf(rintf(v.x * as), -128.0f), 127.0f); o.x = (unsigned short)(__float_as_uint(q) >> 16);
    q = fminf(fmaxf(rintf(v.y * as), -128.0f), 127.0f); o.y = (unsigned short)(__float_as_uint(q) >> 16);
    q = fminf(fmaxf(rintf(v.z * as), -128.0f), 127.0f); o.z = (unsigned short)(__float_as_uint(q) >> 16);
    q = fminf(fmaxf(rintf(v.w * as), -128.0f), 127.0f); o.w = (unsigned short)(__float_as_uint(q) >> 16);
    xo[i] = o;
  }
  if (threadIdx.x == 0) dq[t] = amax / 127.0f;
}

// ---------------------------------------------------------------------------
// bf16-MFMA BitLinear GEMM, 128x128 tiles. Staging via global_load_lds DMA
// (linear LDS dest, XOR-swizzled source cols, swizzled fragment reads) with a
// double-buffered counted-vmcnt pipeline: at 320 blocks (1.25/CU = 1 wave/
// SIMD) the old vmcnt(0) drain exposed full L2 latency every K-step.
// RoPE fused into the epilogue (unchanged from r4).
__global__ __launch_bounds__(256) void k_gemm_mfma(
    const unsigned short* __restrict__ Aq, const unsigned short* __restrict__ Ball,
    const float* __restrict__ adq, const double* __restrict__ sums,
    const float2* __restrict__ ropetab,
    float* __restrict__ oQ, unsigned short* __restrict__ oKhi,
    unsigned short* __restrict__ oKlo,
    float* __restrict__ oV, float* __restrict__ oQN, int mode) {
  __shared__ __attribute__((aligned(16))) unsigned short As[2][128 * 64];
  __shared__ __attribute__((aligned(16))) unsigned short Bs[2][128 * 64];
  const int t = threadIdx.x;
  const int lane = t & 63;
  const int row16 = lane & 15, q = lane >> 4;
  const int w = t >> 6;
  const int wm = (w >> 1) * 64, wn = (w & 1) * 64;
  const int bx = blockIdx.x;
  const int m0 = blockIdx.y * 128;
  const unsigned short* Bp = Ball + (size_t)bx * 128 * 2048;
  const int swr = row16 & 7;                 // fragment-read XOR key

  floatx4 acc[4][4];
#pragma unroll
  for (int g = 0; g < 4; ++g)
#pragma unroll
    for (int h = 0; h < 4; ++h) acc[g][h] = (floatx4){0.f, 0.f, 0.f, 0.f};

  auto stageAB = [&](int k0s, int b) {
#pragma unroll
    for (int i = 0; i < 4; ++i) {
      int c = t + 256 * i;
      int row = c >> 3, g8 = c & 7;
      int sa = (g8 ^ (row & 7)) * 8;         // source col slot swizzle
      gload16(Aq + (size_t)(m0 + row) * 2048 + k0s + sa, &As[b][w * 512 + i * 2048]);
      gload16(Bp + (size_t)row * 2048 + k0s + sa, &Bs[b][w * 512 + i * 2048]);
    }
  };

  stageAB(0, 0);   // prologue: 8 DMA outstanding
  for (int k0 = 0; k0 < 2048; k0 += 64) {
    const int cur = (k0 >> 6) & 1;
    const int kn = (k0 + 64 < 2048) ? k0 + 64 : k0;   // clamped redundant last
    stageAB(kn, cur ^ 1);                             // +8 -> 16 outstanding
    asm volatile("s_waitcnt vmcnt(8)" ::: "memory");  // wait current tile's 8
    __builtin_amdgcn_s_barrier();
#pragma unroll
    for (int kk = 0; kk < 2; ++kk) {
      short8 af[4], bf[4];
      const int sw = ((kk * 4 + q) ^ swr) << 3;
#pragma unroll
      for (int g = 0; g < 4; ++g)
        af[g] = *(const short8*)&As[cur][(wm + g * 16 + row16) * 64 + sw];
#pragma unroll
      for (int h = 0; h < 4; ++h)
        bf[h] = *(const short8*)&Bs[cur][(wn + h * 16 + row16) * 64 + sw];
#pragma unroll
      for (int g = 0; g < 4; ++g)
#pragma unroll
        for (int h = 0; h < 4; ++h)
          acc[g][h] = __builtin_amdgcn_mfma_f32_16x16x32_bf16(af[g], bf[h], acc[g][h], 0, 0, 0);
    }
    __builtin_amdgcn_s_barrier();   // reads of buf[cur] done before it is re-staged
  }
  asm volatile("s_waitcnt vmcnt(0)" ::: "memory");   // drain redundant last prefetch

  float* outp = nullptr; int Nout = 0, nb0; float wdq;
  if (mode == 1)      { outp = oQ;  Nout = 2048; nb0 = bx * 128;        wdq = fmaxf((float)sums[3] * INV_BIG,   1e-5f); }
  else if (bx < 16)   { outp = oQ;  Nout = 2048; nb0 = bx * 128;        wdq = fmaxf((float)sums[0] * INV_BIG,   1e-5f); }
  else if (bx < 20)   {             Nout = 512;  nb0 = (bx - 16) * 128; wdq = fmaxf((float)sums[1] * INV_SMALL, 1e-5f); }
  else if (bx < 24)   { outp = oV;  Nout = 512;  nb0 = (bx - 20) * 128; wdq = fmaxf((float)sums[2] * INV_SMALL, 1e-5f); }
  else                { outp = oQN; Nout = 2048; nb0 = (bx - 24) * 128; wdq = fmaxf((float)sums[4] * INV_BIG,   1e-5f); }

  if (mode == 0 && bx < 20) {
    // RoPE epilogue. head-relative d = (wn + h*16 + row16) & 63 = h*16 + row16.
#pragma unroll
    for (int g = 0; g < 4; ++g)
#pragma unroll
      for (int r = 0; r < 4; ++r) {
        int m = m0 + wm + g * 16 + q * 4 + r;
        float s = adq[m] * wdq;
        float2 cs0 = ropetab[m * 32 + row16];        // d = row16
        float2 cs1 = ropetab[m * 32 + 16 + row16];   // d = 16 + row16
        float v0 = acc[g][0][r] * s, v1 = acc[g][1][r] * s;
        float v2 = acc[g][2][r] * s, v3 = acc[g][3][r] * s;
        float o0 = v0 * cs0.x - v2 * cs0.y;
        float o2 = v2 * cs0.x + v0 * cs0.y;
        float o1 = v1 * cs1.x - v3 * cs1.y;
        float o3 = v3 * cs1.x + v1 * cs1.y;
        if (bx < 16) {   // Q: fp32
          size_t base = (size_t)m * Nout + nb0 + wn;
          outp[base + row16]      = o0;
          outp[base + 16 + row16] = o1;
          outp[base + 32 + row16] = o2;
          outp[base + 48 + row16] = o3;
        } else {
          // K: RN-bsplit into fragment-ordered hi/lo planes.
          // value o_h: key rr = m&63 (tile kt_ = m>>6), d = h*16 + row16.
          int hkv_ = (nb0 + wn) >> 6;
          int kt_ = m >> 6, rr = m & 63;
          size_t tb = ((size_t)(hkv_ * 16 + kt_)) * 4096;
          int lbase = (rr & 15) + ((row16 >> 3) << 4);
          int ntb = (rr >> 4) * 512 + (row16 & 7);
          unsigned short hi, lo; int ix;
          bsplit(o0, hi, lo); ix = ntb + (lbase     ) * 8;          oKhi[tb + ix] = hi; oKlo[tb + ix] = lo;
          bsplit(o1, hi, lo); ix = ntb + (lbase + 32) * 8;          oKhi[tb + ix] = hi; oKlo[tb + ix] = lo;
          bsplit(o2, hi, lo); ix = ntb + (lbase     ) * 8 + 2048;   oKhi[tb + ix] = hi; oKlo[tb + ix] = lo;
          bsplit(o3, hi, lo); ix = ntb + (lbase + 32) * 8 + 2048;   oKhi[tb + ix] = hi; oKlo[tb + ix] = lo;
        }
      }
  } else {
#pragma unroll
    for (int g = 0; g < 4; ++g)
#pragma unroll
      for (int r = 0; r < 4; ++r) {
        int m = m0 + wm + g * 16 + q * 4 + r;
        float s = adq[m] * wdq;
#pragma unroll
        for (int h = 0; h < 4; ++h)
          outp[(size_t)m * Nout + nb0 + wn + h * 16 + row16] = acc[g][h][r] * s;
      }
  }
}

// ---------------------------------------------------------------------------
// O-projection GEMM, 64x64 tiles: grid 32x16 = 512 blocks (2/CU; the old
// 128-tile grid was 128 blocks = half the GPU idle). Same DMA staging +
// counted-vmcnt double buffer.
__global__ __launch_bounds__(256) void k_gemm64(
    const unsigned short* __restrict__ Aq, const unsigned short* __restrict__ Bq,
    const float* __restrict__ adq, const double* __restrict__ sums,
    float* __restrict__ out) {
  __shared__ __attribute__((aligned(16))) unsigned short As[2][64 * 64];
  __shared__ __attribute__((aligned(16))) unsigned short Bs[2][64 * 64];
  const int t = threadIdx.x;
  const int lane = t & 63;
  const int row16 = lane & 15, q = lane >> 4;
  const int w = t >> 6;
  const int wm = (w >> 1) * 32, wn = (w & 1) * 32;
  const int nb0 = blockIdx.x * 64;
  const int m0 = blockIdx.y * 64;
  const int swr = row16 & 7;

  floatx4 acc[2][2];
#pragma unroll
  for (int g = 0; g < 2; ++g)
#pragma unroll
    for (int h = 0; h < 2; ++h) acc[g][h] = (floatx4){0.f, 0.f, 0.f, 0.f};

  auto stageAB = [&](int k0s, int b) {
#pragma unroll
    for (int i = 0; i < 2; ++i) {
      int c = t + 256 * i;
      int row = c >> 3, g8 = c & 7;
      int sa = (g8 ^ (row & 7)) * 8;
      gload16(Aq + (size_t)(m0 + row) * 2048 + k0s + sa, &As[b][w * 512 + i * 2048]);
      gload16(Bq + (size_t)(nb0 + row) * 2048 + k0s + sa, &Bs[b][w * 512 + i * 2048]);
    }
  };

  stageAB(0, 0);
  for (int k0 = 0; k0 < 2048; k0 += 64) {
    const int cur = (k0 >> 6) & 1;
    const int kn = (k0 + 64 < 2048) ? k0 + 64 : k0;
    stageAB(kn, cur ^ 1);
    asm volatile("s_waitcnt vmcnt(4)" ::: "memory");
    __builtin_amdgcn_s_barrier();
#pragma unroll
    for (int kk = 0; kk < 2; ++kk) {
      short8 af[2], bf[2];
      const int sw = ((kk * 4 + q) ^ swr) << 3;
#pragma unroll
      for (int g = 0; g < 2; ++g)
        af[g] = *(const short8*)&As[cur][(wm + g * 16 + row16) * 64 + sw];
#pragma unroll
      for (int h = 0; h < 2; ++h)
        bf[h] = *(const short8*)&Bs[cur][(wn + h * 16 + row16) * 64 + sw];
#pragma unroll
      for (int g = 0; g < 2; ++g)
#pragma unroll
        for (int h = 0; h < 2; ++h)
          acc[g][h] = __builtin_amdgcn_mfma_f32_16x16x32_bf16(af[g], bf[h], acc[g][h], 0, 0, 0);
    }
    __builtin_amdgcn_s_barrier();
  }
  asm volatile("s_waitcnt vmcnt(0)" ::: "memory");

  float wdq = fmaxf((float)sums[3] * INV_BIG, 1e-5f);
#pragma unroll
  for (int g = 0; g < 2; ++g)
#pragma unroll
    for (int r = 0; r < 4; ++r) {
      int m = m0 + wm + g * 16 + q * 4 + r;
      float s = adq[m] * wdq;
#pragma unroll
      for (int h = 0; h < 2; ++h)
        out[(size_t)m * 2048 + nb0 + wn + h * 16 + row16] = acc[g][h][r] * s;
    }
}

// ---------------------------------------------------------------------------
// Merged prep. All outputs are 8KB fragment-ordered ushort tile planes (see
// header comment) so attention loads fragments global->VGPR fully coalesced.
//   blocks [0,1024):    vtKB  (transpose kbv -> V^T, RN-bsplit hi/lo planes)
//   blocks [1024,1152): vtP   (transpose Vb  -> V^T, RN-bsplit hi/lo planes)
//   blocks >= 1152:     kbk   in-place tile split [key][d] -> [hi 8KB | lo 8KB]
__global__ __launch_bounds__(256) void k_prep(
    const float* __restrict__ kbv, const float* __restrict__ Vb,
    unsigned short* __restrict__ vtKBhi, unsigned short* __restrict__ vtPhi,
    float* __restrict__ kbk) {
  const int b = blockIdx.x;
  const int t = threadIdx.x;
  if (b >= 1152) {
    float* tile = kbk + (size_t)(b - 1152) * 4096;   // 64x64 f32 [key][d], contiguous
    float v[2][8];
#pragma unroll
    for (int u = 0; u < 2; ++u) {
      int task = t + 256 * u;            // 512 tasks: key r = task>>3, d-slot s = task&7
      int r = task >> 3, s = task & 7;
      *(float4*)&v[u][0] = *(const float4*)(tile + r * 64 + s * 8);
      *(float4*)&v[u][4] = *(const float4*)(tile + r * 64 + s * 8 + 4);
    }
    __syncthreads();                     // all reads before any in-place write
    unsigned short* up = (unsigned short*)tile;
#pragma unroll
    for (int u = 0; u < 2; ++u) {
      int task = t + 256 * u;
      int r = task >> 3, s = task & 7;   // element (key=r, d=s*8+j)
      union { unsigned short u16[8]; uint4 q; } hi, lo;
#pragma unroll
      for (int j = 0; j < 8; ++j) bsplit(v[u][j], hi.u16[j], lo.u16[j]);
      // K-frag: frag = (d>>5)*4 + (key>>4); lane = (key&15) + 16*((d&31)>>3); j = d&7
      size_t off = (size_t)(((s >> 2) * 4 + (r >> 4)) * 512 + ((r & 15) + ((s & 3) << 4)) * 8);
      *(uint4*)(up + off)        = hi.q;
      *(uint4*)(up + 4096 + off) = lo.q;
    }
    return;
  }
  __shared__ float Lf[64 * 65];
  const float* src; unsigned short *dhi, *dlo; int srcStride;
  if (b < 1024) {
    int h = b >> 5, kt = b & 31;
    src = kbv + ((size_t)h * cKB + kt * 64) * 64; srcStride = 64;
    dhi = vtKBhi + (size_t)b * 4096; dlo = dhi + 4194304;
  } else {
    int bb = b - 1024;
    int hkv = bb >> 4, kt = bb & 15;
    src = Vb + (size_t)(kt * 64) * 512 + hkv * 64; srcStride = 512;
    dhi = vtPhi + (size_t)bb * 4096; dlo = dhi + 524288;
  }
#pragma unroll
  for (int i = 0; i < 4; ++i) {
    int c = t + 256 * i;
    int row = c >> 4, c4 = (c & 15) * 4;       // row = key, col = d
    float4 x = *(const float4*)(src + (size_t)row * srcStride + c4);
    Lf[row * 65 + c4 + 0] = x.x;
    Lf[row * 65 + c4 + 1] = x.y;
    Lf[row * 65 + c4 + 2] = x.z;
    Lf[row * 65 + c4 + 3] = x.w;
  }
  __syncthreads();
#pragma unroll
  for (int u = 0; u < 2; ++u) {
    int task = t + 256 * u;                    // d = task>>3, key slot s = task&7
    int d = task >> 3, s = task & 7;           // element (d, key=s*8+j)
    union { unsigned short u16[8]; uint4 q; } hi, lo;
#pragma unroll
    for (int j = 0; j < 8; ++j) bsplit(Lf[(s * 8 + j) * 65 + d], hi.u16[j], lo.u16[j]);
    // V^T-frag: frag = (key>>5)*4 + (d>>4); lane = (d&15) + 16*((key&31)>>3); j = key&7
    size_t off = (size_t)(((s >> 2) * 4 + (d >> 4)) * 512 + ((d & 15) + ((s & 3) << 4)) * 8);
    *(uint4*)(dhi + off) = hi.q;
    *(uint4*)(dlo + off) = lo.q;
  }
}

// ---------------------------------------------------------------------------
// Split-bf16 MFMA flash attention, REGISTER-DIRECT K/V (r4 config — the
// measured latency/locality equilibrium: 512 blocks, 2/CU; KV-split at 4/CU
// thrashed L1/L2 and doubled runtime). Fragment-ordered global tiles load
// straight into VGPRs with coalesced dwordx4; LDS holds only the per-wave P
// transpose. V loads at loop top (hide under QK+softmax); next-K after QK.
__global__ __launch_bounds__(256, 2) void k_attn_mfma(
    const float* __restrict__ Qr, float* qnctx,
    const unsigned short* __restrict__ KPhi,    // prompt K planes, lo at +524288
    const unsigned short* __restrict__ kbkS,    // KB K tiles [h*32+kt][hi 4096 | lo 4096]
    const unsigned short* __restrict__ vtKBhi,  // KB V^T planes, lo at +4194304
    const unsigned short* __restrict__ vtPhi) { // prompt V^T planes, lo at +524288
  __shared__ __attribute__((aligned(16))) unsigned int Pbuf[4][16 * 68];   // per-wave

  const int t = threadIdx.x;
  const int lane = t & 63;
  const int col = lane & 15;
  const int quad = lane >> 4;
  const int w = t >> 6;
  const int h = blockIdx.x;
  const int q0 = blockIdx.y * 64;
  const int hkv = h >> 2;
  const float kbbias = 0.69314718055994531f;   // log(4096)-log(2048)
  unsigned int* Pw = &Pbuf[w][0];
  const int fl = lane * 8;                     // fragment lane offset (ushorts)

  short8 qAh[2], qAl[2];   // kb_q (not rotated)
  short8 qBh[2], qBl[2];   // rotated prompt q
  {
#pragma unroll
    for (int kk = 0; kk < 2; ++kk) {
      const size_t off = (size_t)(q0 + w * 16 + col) * 2048 + h * 64 + kk * 32 + quad * 8;
      float4 a = *(const float4*)(qnctx + off);
      float4 b = *(const float4*)(qnctx + off + 4);
      float xs[8] = {a.x, a.y, a.z, a.w, b.x, b.y, b.z, b.w};
#pragma unroll
      for (int j = 0; j < 8; ++j) {
        unsigned short hi, lo;
        bsplit(xs[j] * 0.125f, hi, lo);   // fold 1/sqrt(64), exact
        qAh[kk][j] = (short)hi; qAl[kk][j] = (short)lo;
      }
      float4 c = *(const float4*)(Qr + off);
      float4 d = *(const float4*)(Qr + off + 4);
      float ys[8] = {c.x, c.y, c.z, c.w, d.x, d.y, d.z, d.w};
#pragma unroll
      for (int j = 0; j < 8; ++j) {
        unsigned short hi, lo;
        bsplit(ys[j] * 0.125f, hi, lo);
        qBh[kk][j] = (short)hi; qBl[kk][j] = (short)lo;
      }
    }
  }

  floatx4 acco[4];
  float m_[4], l_[4];
#pragma unroll
  for (int nt = 0; nt < 4; ++nt) acco[nt] = (floatx4){0.f, 0.f, 0.f, 0.f};
#pragma unroll
  for (int r = 0; r < 4; ++r) { m_[r] = -3.0e38f; l_[r] = 0.f; }

  const int ntiles = 32 + (q0 >> 6) + 1;

  short8 kh[2][4], kl[2][4];   // K fragments (hi/lo), current tile
  short8 vh[2][4], vl[2][4];   // V^T fragments (hi/lo), current tile

  auto loadK = [&](int kt2) {
    const unsigned short *ph, *pl;
    if (kt2 < 32) { const size_t tk = (size_t)(h * 32 + kt2);
                    ph = kbkS + tk * 8192; pl = ph + 4096; }
    else          { const size_t tk = (size_t)(hkv * 16 + (kt2 - 32));
                    ph = KPhi + tk * 4096; pl = ph + 524288; }
#pragma unroll
    for (int kk = 0; kk < 2; ++kk)
#pragma unroll
      for (int nt = 0; nt < 4; ++nt) {
        kh[kk][nt] = *(const short8*)(ph + (kk * 4 + nt) * 512 + fl);
        kl[kk][nt] = *(const short8*)(pl + (kk * 4 + nt) * 512 + fl);
      }
  };
  auto loadV = [&](int kt2) {
    const unsigned short *ph, *pl;
    if (kt2 < 32) { const size_t tk = (size_t)(h * 32 + kt2);
                    ph = vtKBhi + tk * 4096; pl = ph + 4194304; }
    else          { const size_t tk = (size_t)(hkv * 16 + (kt2 - 32));
                    ph = vtPhi + tk * 4096; pl = ph + 524288; }
#pragma unroll
    for (int kk = 0; kk < 2; ++kk)
#pragma unroll
      for (int nt = 0; nt < 4; ++nt) {
        vh[kk][nt] = *(const short8*)(ph + (kk * 4 + nt) * 512 + fl);
        vl[kk][nt] = *(const short8*)(pl + (kk * 4 + nt) * 512 + fl);
      }
  };

  loadK(0);   // prologue

  for (int kt = 0; kt < ntiles; ++kt) {
    const bool isKB = kt < 32;
    loadV(kt);                          // in flight during QK+softmax
    __builtin_amdgcn_s_barrier();       // convergence only (no shared staging)

    floatx4 accs[4];
#pragma unroll
    for (int nt = 0; nt < 4; ++nt) accs[nt] = (floatx4){0.f, 0.f, 0.f, 0.f};
    if (isKB) {
#pragma unroll
      for (int kk = 0; kk < 2; ++kk)
#pragma unroll
        for (int nt = 0; nt < 4; ++nt) {
          accs[nt] = __builtin_amdgcn_mfma_f32_16x16x32_bf16(qAh[kk], kh[kk][nt], accs[nt], 0, 0, 0);
          accs[nt] = __builtin_amdgcn_mfma_f32_16x16x32_bf16(qAl[kk], kh[kk][nt], accs[nt], 0, 0, 0);
          accs[nt] = __builtin_amdgcn_mfma_f32_16x16x32_bf16(qAh[kk], kl[kk][nt], accs[nt], 0, 0, 0);
        }
    } else {
#pragma unroll
      for (int kk = 0; kk < 2; ++kk)
#pragma unroll
        for (int nt = 0; nt < 4; ++nt) {
          accs[nt] = __builtin_amdgcn_mfma_f32_16x16x32_bf16(qBh[kk], kh[kk][nt], accs[nt], 0, 0, 0);
          accs[nt] = __builtin_amdgcn_mfma_f32_16x16x32_bf16(qBl[kk], kh[kk][nt], accs[nt], 0, 0, 0);
          accs[nt] = __builtin_amdgcn_mfma_f32_16x16x32_bf16(qBh[kk], kl[kk][nt], accs[nt], 0, 0, 0);
        }
    }

    // Bias/mask: KB tiles = uniform bias; prompt non-diagonal = none; only the
    // final (diagonal) tile needs the causal mask.
    float sv[4][4];
    if (isKB) {
#pragma unroll
      for (int nt = 0; nt < 4; ++nt)
#pragma unroll
        for (int r = 0; r < 4; ++r) sv[nt][r] = accs[nt][r] + kbbias;
    } else if (kt < ntiles - 1) {
#pragma unroll
      for (int nt = 0; nt < 4; ++nt)
#pragma unroll
        for (int r = 0; r < 4; ++r) sv[nt][r] = accs[nt][r];
    } else {
#pragma unroll
      for (int nt = 0; nt < 4; ++nt) {
        int kl_ = nt * 16 + col;
#pragma unroll
        for (int r = 0; r < 4; ++r) {
          int ql_ = w * 16 + quad * 4 + r;
          sv[nt][r] = accs[nt][r] + ((kl_ <= ql_) ? 0.0f : -1e9f);
        }
      }
    }
#pragma unroll
    for (int r = 0; r < 4; ++r) {
      float rmax = fmaxf(fmaxf(sv[0][r], sv[1][r]), fmaxf(sv[2][r], sv[3][r]));
#pragma unroll
      for (int off = 8; off; off >>= 1) rmax = fmaxf(rmax, __shfl_xor(rmax, off));
      float mnew = fmaxf(m_[r], rmax);
      float alpha = __expf(m_[r] - mnew);
      float psum = 0.f;
#pragma unroll
      for (int nt = 0; nt < 4; ++nt) {
        float p = __expf(sv[nt][r] - mnew);
        sv[nt][r] = p;
        psum += p;
      }
#pragma unroll
      for (int off = 8; off; off >>= 1) psum += __shfl_xor(psum, off);
      l_[r] = l_[r] * alpha + psum;
      m_[r] = mnew;
#pragma unroll
      for (int nt = 0; nt < 4; ++nt) acco[nt][r] *= alpha;
    }

    // Prefetch next tile's K (WAR on kh/kl keeps these after the QK MFMAs;
    // in flight during P-pack + PV). Clamped redundant load on last tile.
    loadK(kt + 1 < ntiles ? kt + 1 : kt);

    // P truncation split -> packed hi|lo<<16 (err <= 2^-16 * p; p in [0,1]).
#pragma unroll
    for (int nt = 0; nt < 4; ++nt)
#pragma unroll
      for (int r = 0; r < 4; ++r) {
        unsigned xb = __float_as_uint(sv[nt][r]);
        float hf = __uint_as_float(xb & 0xffff0000u);
        unsigned db = __float_as_uint(sv[nt][r] - hf);
        Pw[(quad * 4 + r) * 68 + nt * 16 + col] = (xb >> 16) | (db & 0xffff0000u);
      }

#pragma unroll
    for (int kk = 0; kk < 2; ++kk) {
      uint4 pa = *(const uint4*)&Pw[col * 68 + kk * 32 + quad * 8];
      uint4 pb = *(const uint4*)&Pw[col * 68 + kk * 32 + quad * 8 + 4];
      union { unsigned int u[4]; short8 s; } uh, ul;
      uh.u[0] = (pa.x & 0xffffu) | (pa.y << 16);
      uh.u[1] = (pa.z & 0xffffu) | (pa.w << 16);
      uh.u[2] = (pb.x & 0xffffu) | (pb.y << 16);
      uh.u[3] = (pb.z & 0xffffu) | (pb.w << 16);
      ul.u[0] = (pa.x >> 16) | (pa.y & 0xffff0000u);
      ul.u[1] = (pa.z >> 16) | (pa.w & 0xffff0000u);
      ul.u[2] = (pb.x >> 16) | (pb.y & 0xffff0000u);
      ul.u[3] = (pb.z >> 16) | (pb.w & 0xffff0000u);
      short8 ph8 = uh.s, pl8 = ul.s;
#pragma unroll
      for (int nt = 0; nt < 4; ++nt) {
        acco[nt] = __builtin_amdgcn_mfma_f32_16x16x32_bf16(ph8, vh[kk][nt], acco[nt], 0, 0, 0);
        acco[nt] = __builtin_amdgcn_mfma_f32_16x16x32_bf16(pl8, vh[kk][nt], acco[nt], 0, 0, 0);
        acco[nt] = __builtin_amdgcn_mfma_f32_16x16x32_bf16(ph8, vl[kk][nt], acco[nt], 0, 0, 0);
      }
    }
  }

#pragma unroll
  for (int r = 0; r < 4; ++r) {
    float linv = 1.0f / l_[r];
#pragma unroll
    for (int nt = 0; nt < 4; ++nt)
      qnctx[(size_t)(q0 + w * 16 + quad * 4 + r) * 2048 + h * 64 + nt * 16 + col] =
          acco[nt][r] * linv;
  }
}

// ---------------------------------------------------------------------------
extern "C" void kernel_launch(void* const* d_in, const int* in_sizes, int n_in,
                              void* d_out, int out_size, void* d_ws, size_t ws_size,
                              hipStream_t stream) {
  (void)in_sizes; (void)n_in; (void)out_size; (void)ws_size;
  const float* hidden = (const float*)d_in[0];
  float* kbk = (float*)d_in[2];              // tile-split in place (restored each launch)
  const float* kbv = (const float*)d_in[3];
  const float* Wq  = (const float*)d_in[4];
  const float* Wk  = (const float*)d_in[5];
  const float* Wv  = (const float*)d_in[6];
  const float* Wo  = (const float*)d_in[7];
  const float* Wqn = (const float*)d_in[8];
  const int*   pos = (const int*)d_in[9];

  char* ws = (char*)d_ws;
  double* sums = (double*)(ws + WS_SUMS);
  float* dq1 = (float*)(ws + WS_DQ1);
  float* dq2 = (float*)(ws + WS_DQ2);
  unsigned short* xq   = (unsigned short*)(ws + WS_XQ);
  unsigned short* wall = (unsigned short*)(ws + WS_WALL);
  unsigned short* vtKBhi = (unsigned short*)(ws + WS_WALL);              // after GEMM
  unsigned short* vtPhi  = (unsigned short*)(ws + WS_WALL + 16777216);   // after GEMM
  unsigned short* wqo  = (unsigned short*)(ws + WS_QB);                  // after attn
  float* Qb  = (float*)(ws + WS_QB);
  unsigned short* KPhi = (unsigned short*)(ws + WS_KB);                  // prompt K hi
  unsigned short* KPlo = KPhi + 524288;                                  // prompt K lo
  float* Vb  = (float*)(ws + WS_VB);
  float* QNC = (float*)(ws + WS_QN);   // kb_q, then CTX
  float2* ropetab = (float2*)(ws + WS_ROPET);

  hipMemsetAsync(sums, 0, 64, stream);

  k_ropetab<<<128, 256, 0, stream>>>(pos, ropetab);
  k_abssum5<<<dim3(128, 5), 256, 0, stream>>>(Wq, Wk, Wv, Wo, Wqn, sums);
  k_wquant4<<<10240, 256, 0, stream>>>(Wq, Wk, Wv, Wqn, wall, sums);
  k_aquant<<<cQ, 256, 0, stream>>>(hidden, xq, dq1, cH);

  // Fused Q/K/V/QN GEMM with RoPE epilogue: 128x128 tiles, grid 40x8
  k_gemm_mfma<<<dim3(40, 8), 256, 0, stream>>>(xq, wall, dq1, sums, ropetab,
                                               Qb, KPhi, KPlo, Vb, QNC, 0);

  // V transposes (1152 blocks) + kbk in-place tile split (1024 blocks)
  k_prep<<<1152 + 1024, 256, 0, stream>>>(kbv, Vb, vtKBhi, vtPhi, kbk);

  k_attn_mfma<<<dim3(cNH, cQ / 64), 256, 0, stream>>>(
      Qb, QNC, KPhi, (const unsigned short*)kbk, vtKBhi, vtPhi);

  k_wquant<<<4096, 256, 0, stream>>>(Wo, wqo, sums + 3, INV_BIG);
  k_aquant<<<cQ, 256, 0, stream>>>(QNC, xq, dq2, cH);

  // O projection: 64x64 tiles, grid 32x16 = 512 blocks (2/CU)
  k_gemm64<<<dim3(32, 16), 256, 0, stream>>>(xq, wqo, dq2, sums, (float*)d_out);
}